// Round 16
// baseline (128.745 us; speedup 1.0000x reference)
//
#include <hip/hip_runtime.h>
#include <hip/hip_bf16.h>

// out[t,l] = sum_{ijk} p1[t,i] p2[t,j] p3[t,k] grid[i,j,k,l]
// GEMM M=16384, K=4096 (k=i*256+j*16+kk), N=768; A built in registers.
// v15: 1-WAVE workgroups, wave-private B staging, ZERO barriers.
//      Wave tile 64x96 (mr=2,nf=3), BK=32, per-wave counted vmcnt(6).
//      Conflict-free derived LDS swizzle. Grid 2048 = 256-M x 8-N slices,
//      XCD-sliced (each XCD owns one 96-col B slice -> L2-resident).

using f32x2  = __attribute__((ext_vector_type(2))) float;
using f32x4  = __attribute__((ext_vector_type(4))) float;
using f32x16 = __attribute__((ext_vector_type(16))) float;
using half8  = __attribute__((ext_vector_type(8))) _Float16;
using half2v = __attribute__((ext_vector_type(2))) _Float16;
typedef unsigned short ushort_t;
typedef unsigned int uint_t;

typedef const __attribute__((address_space(1))) void* gptr_t;
typedef __attribute__((address_space(3))) void* lptr_t;

#define PSTRIDE 52            // p row stride (floats)

static __device__ __forceinline__ ushort_t f2h_bits(float x) {
  union { _Float16 h; ushort_t u; } c;
  c.h = (_Float16)x;          // RNE
  return c.u;
}

static __device__ __forceinline__ half2v cvt_pkrtz2(float a, float b) {
  auto r = __builtin_amdgcn_cvt_pkrtz(a, b);
  union { decltype(r) i; half2v o; } u;
  u.i = r;
  return u.o;
}

// ---------------------------------------------------------------------------
// Kernel 1: grid transpose -> gT f16 [by=0..11]; W -> wfrag B-frags [by=12]
// ---------------------------------------------------------------------------
__global__ __launch_bounds__(256) void k_pack(const float* __restrict__ g,
                                              ushort_t* __restrict__ gT,
                                              const float* __restrict__ W1,
                                              const float* __restrict__ W2,
                                              const float* __restrict__ W3,
                                              ushort_t* __restrict__ wfrag) {
  const int tx = threadIdx.x;
  if (blockIdx.y == 12) {
    if (blockIdx.x >= 9) return;
#pragma unroll
    for (int j = 0; j < 16; ++j) {
      const int u = blockIdx.x * 4096 + tx * 16 + j;   // 0..36863
      const int e = u & 7;
      const int l = (u >> 3) & 63;
      const int frag = u >> 9;                         // ks*3+nf
      const int ks = frag / 3, nf = frag % 3;
      const int d = ks * 32 + 8 * (l >> 4) + e;
      const int col = l & 15;
      const float* Wsel = (nf == 0) ? W1 : (nf == 1) ? W2 : W3;
      wfrag[u] = f2h_bits(Wsel[d * 16 + col]);
    }
    return;
  }
  __shared__ ushort_t tile[64][65];
  const int r0 = blockIdx.x * 64;   // ijk base
  const int c0 = blockIdx.y * 64;   // l base
#pragma unroll
  for (int it = 0; it < 4; ++it) {
    const int idx = tx + it * 256;
    const int r = idx >> 4;
    const int c = (idx & 15) << 2;
    const float4 v = *(const float4*)(g + (size_t)(r0 + r) * 768 + (c0 + c));
    tile[c + 0][r] = f2h_bits(v.x);
    tile[c + 1][r] = f2h_bits(v.y);
    tile[c + 2][r] = f2h_bits(v.z);
    tile[c + 3][r] = f2h_bits(v.w);
  }
  __syncthreads();
#pragma unroll
  for (int it = 0; it < 4; ++it) {
    const int idx = tx + it * 256;
    const int r = idx >> 4;
    const int c = (idx & 15) << 2;
    ushort4 o;
    o.x = tile[r][c + 0]; o.y = tile[r][c + 1];
    o.z = tile[r][c + 2]; o.w = tile[r][c + 3];
    *(ushort4*)(gT + (size_t)(c0 + r) * 4096 + (r0 + c)) = o;
  }
}

// ---------------------------------------------------------------------------
// Kernel 2: MFMA prep (v13, unchanged). p[t][48] = softmax16((x@W+b)/temp).
// ---------------------------------------------------------------------------
__global__ __launch_bounds__(256) void k_prep(const float* __restrict__ x,
                                              const ushort_t* __restrict__ wfrag,
                                              const float* __restrict__ b1,
                                              const float* __restrict__ b2,
                                              const float* __restrict__ b3,
                                              const float* __restrict__ temp,
                                              float* __restrict__ p) {
  const int tid = threadIdx.x;
  const int lane = tid & 63;
  const int wv = tid >> 6;
  const int t0w = blockIdx.x * 64 + wv * 16;  // wave's token base
  const int m = lane & 15;                    // A row / C col
  const int q = lane >> 4;                    // 0..3

  const float* xrow = x + (size_t)(t0w + m) * 768 + q * 8;

  f32x4 acc[3];
#pragma unroll
  for (int nf = 0; nf < 3; ++nf) acc[nf] = (f32x4){0.f, 0.f, 0.f, 0.f};

  const ushort_t* wf = wfrag + lane * 8;
#pragma unroll
  for (int ks = 0; ks < 24; ++ks) {
    const f32x4 xa = *(const f32x4*)(xrow + ks * 32);
    const f32x4 xb = *(const f32x4*)(xrow + ks * 32 + 4);
    union { half2v h2[4]; half8 h8; } pk;
    pk.h2[0] = cvt_pkrtz2(xa[0], xa[1]);
    pk.h2[1] = cvt_pkrtz2(xa[2], xa[3]);
    pk.h2[2] = cvt_pkrtz2(xb[0], xb[1]);
    pk.h2[3] = cvt_pkrtz2(xb[2], xb[3]);
    const half8 a = pk.h8;
#pragma unroll
    for (int nf = 0; nf < 3; ++nf) {
      const half8 w = *(const half8*)&wf[(size_t)(ks * 3 + nf) * 512];
      acc[nf] = __builtin_amdgcn_mfma_f32_16x16x32_f16(a, w, acc[nf], 0, 0, 0);
    }
  }

  const float invT = 1.0f / temp[0];
  float z[3][4];
  const float bias[3] = {b1[m], b2[m], b3[m]};
#pragma unroll
  for (int nf = 0; nf < 3; ++nf)
#pragma unroll
    for (int r = 0; r < 4; ++r) z[nf][r] = (acc[nf][r] + bias[nf]) * invT;

#pragma unroll
  for (int grp = 0; grp < 3; ++grp) {
    float mx[4], sm[4];
#pragma unroll
    for (int r = 0; r < 4; ++r) mx[r] = z[grp][r];
#pragma unroll
    for (int msk = 1; msk < 16; msk <<= 1)
#pragma unroll
      for (int r = 0; r < 4; ++r) mx[r] = fmaxf(mx[r], __shfl_xor(mx[r], msk));
#pragma unroll
    for (int r = 0; r < 4; ++r) { z[grp][r] = __expf(z[grp][r] - mx[r]); sm[r] = z[grp][r]; }
#pragma unroll
    for (int msk = 1; msk < 16; msk <<= 1)
#pragma unroll
      for (int r = 0; r < 4; ++r) sm[r] += __shfl_xor(sm[r], msk);
#pragma unroll
    for (int r = 0; r < 4; ++r) z[grp][r] /= sm[r];
  }

#pragma unroll
  for (int r = 0; r < 4; ++r) {
    float* prow = p + (size_t)(t0w + 4 * q + r) * PSTRIDE + m;
#pragma unroll
    for (int grp = 0; grp < 3; ++grp) prow[grp * 16] = z[grp][r];
  }
}

// ---------------------------------------------------------------------------
// Kernel 3: GEMM, 1-wave blocks, barrier-free. Block = 64 tokens x 96 cols.
// BK=32 (128 kt). Wave stages its own 96x32 B-slice: 6 global_load_lds of
// 16B x 64 lanes; LDS row-major [96][32] with chunk swizzle c^((row>>1)&3)
// (conflict-free reads); counted vmcnt(6). p1 in 2KB LDS (own-wave, no bar).
// ---------------------------------------------------------------------------
__global__ __launch_bounds__(64) void k_gemm(const float* __restrict__ p_g,
                                             const ushort_t* __restrict__ gT,
                                             float* __restrict__ out) {
  __shared__ ushort_t Bt[2][96 * 32];         // 12,288 B
  __shared__ ushort_t p1h[16 * 64];           //  2,048 B  [i][token] f16

  const int lane = threadIdx.x;
  const int g = lane >> 5;                    // k-half 0/1
  const int l31 = lane & 31;

  // XCD-sliced mapping over 2048 blocks: n-slice = f&7 (one per XCD),
  // m-tile = f>>3.
  const int f = blockIdx.x;
  const int m0 = (f >> 3) * 64;               // token base
  const int n0 = (f & 7) * 96;                // latent base

  // p1h build: lane l owns token l; write [i][token]
  {
    const float* pr = p_g + (size_t)(m0 + lane) * PSTRIDE;
#pragma unroll
    for (int qq = 0; qq < 4; ++qq) {
      const f32x4 v = *(const f32x4*)(pr + qq * 4);
#pragma unroll
      for (int e = 0; e < 4; ++e) p1h[(qq * 4 + e) * 64 + lane] = f2h_bits(v[e]);
    }
  }

  // per-lane p2 (16 broadcast pairs) / p3 (own k-half) for rows l31, l31+32
  half2v p2h[2][16];
  float p3r[2][8];
#pragma unroll
  for (int mr = 0; mr < 2; ++mr) {
    const float* pr = p_g + (size_t)(m0 + mr * 32 + l31) * PSTRIDE;
#pragma unroll
    for (int qq = 0; qq < 4; ++qq) {
      const f32x4 v = *(const f32x4*)(pr + 16 + qq * 4);
#pragma unroll
      for (int e = 0; e < 4; ++e)
        p2h[mr][qq * 4 + e] = cvt_pkrtz2(v[e], v[e]);
    }
#pragma unroll
    for (int qq = 0; qq < 2; ++qq) {
      const f32x4 v = *(const f32x4*)(pr + 32 + 8 * g + qq * 4);
      p3r[mr][qq * 4 + 0] = v[0]; p3r[mr][qq * 4 + 1] = v[1];
      p3r[mr][qq * 4 + 2] = v[2]; p3r[mr][qq * 4 + 3] = v[3];
    }
  }

  // staging: load q covers rows q*16+(lane>>2), slot-chunk lane&3;
  // source chunk = (lane&3) ^ ((lane>>3)&3)  [inverse of read swizzle]
  const int srow = lane >> 2;
  const int schunk = (lane & 3) ^ ((lane >> 3) & 3);
  const ushort_t* sbase = gT + (size_t)(n0 + srow) * 4096 + schunk * 8;
  auto stage = [&](int buf, int kt) {
    const ushort_t* src = sbase + kt * 32;
#pragma unroll
    for (int q = 0; q < 6; ++q) {
      __builtin_amdgcn_global_load_lds((gptr_t)(src + (size_t)q * 16 * 4096),
                                       (lptr_t)&Bt[buf][q * 512], 16, 0, 0);
    }
  };

  f32x16 acc[2][3];
#pragma unroll
  for (int mr = 0; mr < 2; ++mr)
#pragma unroll
    for (int nf = 0; nf < 3; ++nf)
#pragma unroll
      for (int e = 0; e < 16; ++e) acc[mr][nf][e] = 0.f;

  stage(0, 0);

  // read swizzle: chunk = (2s+g) ^ ((l31>>1)&3); row = nf*32 + l31
  const int rsw = (l31 >> 1) & 3;

  for (int io = 0; io < 16; ++io) {           // i = io (k>>8)
    half2v p1p3h[2][4];
#pragma unroll
    for (int mr = 0; mr < 2; ++mr) {
      union { ushort_t u; _Float16 h; } c;
      c.u = p1h[io * 64 + mr * 32 + l31];
      const float p1v = (float)c.h;
#pragma unroll
      for (int qq = 0; qq < 4; ++qq)
        p1p3h[mr][qq] = cvt_pkrtz2(p1v * p3r[mr][2 * qq],
                                   p1v * p3r[mr][2 * qq + 1]);
    }
#pragma unroll
    for (int u = 0; u < 8; ++u) {             // kt = io*8+u; buf = kt&1 = u&1
      const int kt = io * 8 + u;
      if (kt < 127) {
        stage((u & 1) ^ 1, kt + 1);
        asm volatile("s_waitcnt vmcnt(6)" ::: "memory");   // kt's 6 landed
      } else {
        asm volatile("s_waitcnt vmcnt(0)" ::: "memory");
      }
      const ushort_t* bbuf = Bt[u & 1];

#pragma unroll
      for (int s = 0; s < 2; ++s) {
        const int cd = 2 * s + g;
        half8 b[3];
#pragma unroll
        for (int nf = 0; nf < 3; ++nf) {
          const int r = nf * 32 + l31;
          b[nf] = *(const half8*)&bbuf[r * 32 + ((cd ^ rsw) << 3)];
        }
        const int j = (2 * u + s) & 15;       // static p2 index
        half8 a[2];
#pragma unroll
        for (int mr = 0; mr < 2; ++mr) {
          union { half2v h2[4]; half8 h8; } pk;
#pragma unroll
          for (int qq = 0; qq < 4; ++qq) pk.h2[qq] = p2h[mr][j] * p1p3h[mr][qq];
          a[mr] = pk.h8;
        }
        __builtin_amdgcn_s_setprio(1);
#pragma unroll
        for (int mr = 0; mr < 2; ++mr)
#pragma unroll
          for (int nf = 0; nf < 3; ++nf)
            acc[mr][nf] = __builtin_amdgcn_mfma_f32_32x32x16_f16(a[mr], b[nf], acc[mr][nf], 0, 0, 0);
        __builtin_amdgcn_s_setprio(0);
      }
    }
  }

  // epilogue: 32x32 C/D: col = lane&31, row = (reg&3)+8*(reg>>2)+4*(lane>>5)
#pragma unroll
  for (int mr = 0; mr < 2; ++mr)
#pragma unroll
    for (int nf = 0; nf < 3; ++nf)
#pragma unroll
      for (int reg = 0; reg < 16; ++reg) {
        const int row = (reg & 3) + 8 * (reg >> 2) + 4 * g;
        const int t = m0 + mr * 32 + row;
        out[(size_t)t * 768 + n0 + nf * 32 + l31] = acc[mr][nf][reg];
      }
}

// ---------------------------------------------------------------------------
extern "C" void kernel_launch(void* const* d_in, const int* in_sizes, int n_in,
                              void* d_out, int out_size, void* d_ws, size_t ws_size,
                              hipStream_t stream) {
  (void)in_sizes; (void)n_in; (void)out_size; (void)ws_size;
  const float* x    = (const float*)d_in[0];
  const float* W1   = (const float*)d_in[1];
  const float* b1   = (const float*)d_in[2];
  const float* W2   = (const float*)d_in[3];
  const float* b2   = (const float*)d_in[4];
  const float* W3   = (const float*)d_in[5];
  const float* b3   = (const float*)d_in[6];
  const float* grid = (const float*)d_in[7];
  const float* temp = (const float*)d_in[8];
  float* out = (float*)d_out;

  // ws: gT f16 [768][4096] = 6,291,456 B ; p f32 [16384][52] = 3,407,872 B ;
  //     wfrag f16 = 73,728 B
  ushort_t* gT = (ushort_t*)d_ws;
  float* p = (float*)((char*)d_ws + 6291456);
  ushort_t* wfrag = (ushort_t*)((char*)d_ws + 6291456 + 3407872);

  k_pack<<<dim3(64, 13), 256, 0, stream>>>(grid, gT, W1, W2, W3, wfrag);
  k_prep<<<dim3(256), 256, 0, stream>>>(x, wfrag, b1, b2, b3, temp, p);
  k_gemm<<<dim3(2048), 64, 0, stream>>>(p, gT, out);
}

// Round 17
// 118.945 us; speedup vs baseline: 1.0824x; 1.0824x over previous
//
#include <hip/hip_runtime.h>
#include <hip/hip_bf16.h>

// out[t,l] = sum_{ijk} p1[t,i] p2[t,j] p3[t,k] grid[i,j,k,l]
// GEMM M=16384, K=4096 (k=i*256+j*16+kk), N=768; A built in registers.
// v16 = v13 (champion: 95us gemm + MFMA prep, 106 total) with one micro:
//       stage(kt+1) issued at TOP of kt body (max flight time; DMA LDS
//       writes overlap ds_read phase, not MFMA phase).

using f32x2  = __attribute__((ext_vector_type(2))) float;
using f32x4  = __attribute__((ext_vector_type(4))) float;
using f32x16 = __attribute__((ext_vector_type(16))) float;
using half8  = __attribute__((ext_vector_type(8))) _Float16;
using half2v = __attribute__((ext_vector_type(2))) _Float16;
typedef unsigned short ushort_t;
typedef unsigned int uint_t;

typedef const __attribute__((address_space(1))) void* gptr_t;
typedef __attribute__((address_space(3))) void* lptr_t;

#define PSTRIDE 52            // p row stride (floats)

static __device__ __forceinline__ ushort_t f2h_bits(float x) {
  union { _Float16 h; ushort_t u; } c;
  c.h = (_Float16)x;          // RNE
  return c.u;
}

static __device__ __forceinline__ half2v cvt_pkrtz2(float a, float b) {
  auto r = __builtin_amdgcn_cvt_pkrtz(a, b);
  union { decltype(r) i; half2v o; } u;
  u.i = r;
  return u.o;
}

// ---------------------------------------------------------------------------
// Kernel 1: grid transpose -> gT f16 [by=0..11]; W -> wfrag B-frags [by=12]
// ---------------------------------------------------------------------------
__global__ __launch_bounds__(256) void k_pack(const float* __restrict__ g,
                                              ushort_t* __restrict__ gT,
                                              const float* __restrict__ W1,
                                              const float* __restrict__ W2,
                                              const float* __restrict__ W3,
                                              ushort_t* __restrict__ wfrag) {
  const int tx = threadIdx.x;
  if (blockIdx.y == 12) {
    if (blockIdx.x >= 9) return;
#pragma unroll
    for (int j = 0; j < 16; ++j) {
      const int u = blockIdx.x * 4096 + tx * 16 + j;   // 0..36863
      const int e = u & 7;
      const int l = (u >> 3) & 63;
      const int frag = u >> 9;                         // ks*3+nf
      const int ks = frag / 3, nf = frag % 3;
      const int d = ks * 32 + 8 * (l >> 4) + e;
      const int col = l & 15;
      const float* Wsel = (nf == 0) ? W1 : (nf == 1) ? W2 : W3;
      wfrag[u] = f2h_bits(Wsel[d * 16 + col]);
    }
    return;
  }
  __shared__ ushort_t tile[64][65];
  const int r0 = blockIdx.x * 64;   // ijk base
  const int c0 = blockIdx.y * 64;   // l base
#pragma unroll
  for (int it = 0; it < 4; ++it) {
    const int idx = tx + it * 256;
    const int r = idx >> 4;
    const int c = (idx & 15) << 2;
    const float4 v = *(const float4*)(g + (size_t)(r0 + r) * 768 + (c0 + c));
    tile[c + 0][r] = f2h_bits(v.x);
    tile[c + 1][r] = f2h_bits(v.y);
    tile[c + 2][r] = f2h_bits(v.z);
    tile[c + 3][r] = f2h_bits(v.w);
  }
  __syncthreads();
#pragma unroll
  for (int it = 0; it < 4; ++it) {
    const int idx = tx + it * 256;
    const int r = idx >> 4;
    const int c = (idx & 15) << 2;
    ushort4 o;
    o.x = tile[r][c + 0]; o.y = tile[r][c + 1];
    o.z = tile[r][c + 2]; o.w = tile[r][c + 3];
    *(ushort4*)(gT + (size_t)(c0 + r) * 4096 + (r0 + c)) = o;
  }
}

// ---------------------------------------------------------------------------
// Kernel 2: MFMA prep (v13, unchanged). p[t][48] = softmax16((x@W+b)/temp).
// ---------------------------------------------------------------------------
__global__ __launch_bounds__(256) void k_prep(const float* __restrict__ x,
                                              const ushort_t* __restrict__ wfrag,
                                              const float* __restrict__ b1,
                                              const float* __restrict__ b2,
                                              const float* __restrict__ b3,
                                              const float* __restrict__ temp,
                                              float* __restrict__ p) {
  const int tid = threadIdx.x;
  const int lane = tid & 63;
  const int wv = tid >> 6;
  const int t0w = blockIdx.x * 64 + wv * 16;  // wave's token base
  const int m = lane & 15;                    // A row / C col
  const int q = lane >> 4;                    // 0..3

  const float* xrow = x + (size_t)(t0w + m) * 768 + q * 8;

  f32x4 acc[3];
#pragma unroll
  for (int nf = 0; nf < 3; ++nf) acc[nf] = (f32x4){0.f, 0.f, 0.f, 0.f};

  const ushort_t* wf = wfrag + lane * 8;
#pragma unroll
  for (int ks = 0; ks < 24; ++ks) {
    const f32x4 xa = *(const f32x4*)(xrow + ks * 32);
    const f32x4 xb = *(const f32x4*)(xrow + ks * 32 + 4);
    union { half2v h2[4]; half8 h8; } pk;
    pk.h2[0] = cvt_pkrtz2(xa[0], xa[1]);
    pk.h2[1] = cvt_pkrtz2(xa[2], xa[3]);
    pk.h2[2] = cvt_pkrtz2(xb[0], xb[1]);
    pk.h2[3] = cvt_pkrtz2(xb[2], xb[3]);
    const half8 a = pk.h8;
#pragma unroll
    for (int nf = 0; nf < 3; ++nf) {
      const half8 w = *(const half8*)&wf[(size_t)(ks * 3 + nf) * 512];
      acc[nf] = __builtin_amdgcn_mfma_f32_16x16x32_f16(a, w, acc[nf], 0, 0, 0);
    }
  }

  const float invT = 1.0f / temp[0];
  float z[3][4];
  const float bias[3] = {b1[m], b2[m], b3[m]};
#pragma unroll
  for (int nf = 0; nf < 3; ++nf)
#pragma unroll
    for (int r = 0; r < 4; ++r) z[nf][r] = (acc[nf][r] + bias[nf]) * invT;

#pragma unroll
  for (int grp = 0; grp < 3; ++grp) {
    float mx[4], sm[4];
#pragma unroll
    for (int r = 0; r < 4; ++r) mx[r] = z[grp][r];
#pragma unroll
    for (int msk = 1; msk < 16; msk <<= 1)
#pragma unroll
      for (int r = 0; r < 4; ++r) mx[r] = fmaxf(mx[r], __shfl_xor(mx[r], msk));
#pragma unroll
    for (int r = 0; r < 4; ++r) { z[grp][r] = __expf(z[grp][r] - mx[r]); sm[r] = z[grp][r]; }
#pragma unroll
    for (int msk = 1; msk < 16; msk <<= 1)
#pragma unroll
      for (int r = 0; r < 4; ++r) sm[r] += __shfl_xor(sm[r], msk);
#pragma unroll
    for (int r = 0; r < 4; ++r) z[grp][r] /= sm[r];
  }

#pragma unroll
  for (int r = 0; r < 4; ++r) {
    float* prow = p + (size_t)(t0w + 4 * q + r) * PSTRIDE + m;
#pragma unroll
    for (int grp = 0; grp < 3; ++grp) prow[grp * 16] = z[grp][r];
  }
}

// ---------------------------------------------------------------------------
// Kernel 3: GEMM champion (v5/v13 schedule). BM=128 BN=192 BK=64, 4 waves
// 2x2, wave tile 64x96, mfma_32x32x16_f16, 2-buffer drain loop. v16 micro:
// stage(kt+1) first in body.
// ---------------------------------------------------------------------------
__global__ __launch_bounds__(256, 2) void k_gemm(const float* __restrict__ p_g,
                                                 const ushort_t* __restrict__ gT,
                                                 float* __restrict__ out) {
  __shared__ ushort_t Bt[2][192 * 64];        // 49,152 B
  __shared__ float p1T[16 * 128];             //  8,192 B

  const int tid = threadIdx.x;
  const int lane = tid & 63;
  const int wv = __builtin_amdgcn_readfirstlane(tid >> 6);
  const int wm = wv >> 1, wn = wv & 1;
  const int g = lane >> 5;                    // k-half 0/1
  const int l31 = lane & 31;

  // XCD-aware swizzle over 512 blocks (512 % 8 == 0 -> bijective)
  const int f = blockIdx.y * 128 + blockIdx.x;
  const int w = (f & 7) * 64 + (f >> 3);
  const int m0 = (w & 127) * 128;
  const int n0 = (w >> 7) * 192;

  // p1T[i][row] cooperative build (f32)
  if (tid < 128) {
    const float* pr = p_g + (size_t)(m0 + tid) * PSTRIDE;
#pragma unroll
    for (int qq = 0; qq < 4; ++qq) {
      const f32x4 v = *(const f32x4*)(pr + qq * 4);
#pragma unroll
      for (int e = 0; e < 4; ++e) p1T[(qq * 4 + e) * 128 + tid] = v[e];
    }
  }

  // per-lane p2 (16 f16-broadcast pairs) and p3 (own k-half, 8 f32) per m-rep
  const int rowA0 = m0 + wm * 64 + l31;
  half2v p2h[2][16];
  float p3r[2][8];
#pragma unroll
  for (int mr = 0; mr < 2; ++mr) {
    const float* pr = p_g + (size_t)(rowA0 + mr * 32) * PSTRIDE;
#pragma unroll
    for (int qq = 0; qq < 4; ++qq) {
      const f32x4 v = *(const f32x4*)(pr + 16 + qq * 4);
#pragma unroll
      for (int e = 0; e < 4; ++e)
        p2h[mr][qq * 4 + e] = cvt_pkrtz2(v[e], v[e]);
    }
#pragma unroll
    for (int qq = 0; qq < 2; ++qq) {
      const f32x4 v = *(const f32x4*)(pr + 32 + 8 * g + qq * 4);
      p3r[mr][qq * 4 + 0] = v[0]; p3r[mr][qq * 4 + 1] = v[1];
      p3r[mr][qq * 4 + 2] = v[2]; p3r[mr][qq * 4 + 3] = v[3];
    }
  }

  // B staging: linear LDS dest + inverse-swizzled source (16B chunks)
  const int srow = wv * 48 + (lane >> 3);
  const int schunk = (lane & 7) ^ (lane >> 3);
  const ushort_t* sbase = gT + (size_t)(n0 + srow) * 4096 + schunk * 8;
  auto stage = [&](int buf, int kt) {
    const ushort_t* src = sbase + kt * 64;
#pragma unroll
    for (int qq = 0; qq < 6; ++qq) {
      __builtin_amdgcn_global_load_lds((gptr_t)(src + (size_t)qq * 8 * 4096),
                                       (lptr_t)&Bt[buf][(wv * 48 + qq * 8) * 64], 16, 0, 0);
    }
  };

  f32x16 acc[2][3];
#pragma unroll
  for (int mr = 0; mr < 2; ++mr)
#pragma unroll
    for (int nf = 0; nf < 3; ++nf)
#pragma unroll
      for (int e = 0; e < 16; ++e) acc[mr][nf][e] = 0.f;

  stage(0, 0);
  asm volatile("s_waitcnt vmcnt(0) lgkmcnt(0)" ::: "memory");
  __builtin_amdgcn_s_barrier();

  const int rowLoc0 = wm * 64 + l31;
  for (int io = 0; io < 16; ++io) {           // i-index (p1)
    half2v p1p3h[2][4];
#pragma unroll
    for (int mr = 0; mr < 2; ++mr) {
      const float p1v = p1T[io * 128 + rowLoc0 + mr * 32];
#pragma unroll
      for (int qq = 0; qq < 4; ++qq)
        p1p3h[mr][qq] = cvt_pkrtz2(p1v * p3r[mr][2 * qq],
                                   p1v * p3r[mr][2 * qq + 1]);
    }
#pragma unroll
    for (int kq = 0; kq < 4; ++kq) {
      const int kt = io * 4 + kq;
      const ushort_t* bbuf = Bt[kq & 1];

      // v16: prefetch next K64 tile FIRST (max flight; LDS writes overlap
      // the ds_read phase). Buffer (kq+1)&1 was last read before kt-1's
      // barrier -> safe.
      if (kq < 3 || io < 15) stage((kq + 1) & 1, kt + 1);

      // all 12 B-fragment reads (counted lgkm waits by compiler)
      half8 b[4][3];
#pragma unroll
      for (int s = 0; s < 4; ++s) {
        const int cd = 2 * s + g;
#pragma unroll
        for (int nf = 0; nf < 3; ++nf) {
          const int r = wn * 96 + nf * 32 + l31;
          b[s][nf] = *(const half8*)&bbuf[r * 64 + ((cd ^ (r & 7)) << 3)];
        }
      }

#pragma unroll
      for (int s = 0; s < 4; ++s) {
        const int j = kq * 4 + s;             // static p2 index
        half8 a[2];
#pragma unroll
        for (int mr = 0; mr < 2; ++mr) {
          union { half2v h2[4]; half8 h8; } pk;
#pragma unroll
          for (int qq = 0; qq < 4; ++qq) pk.h2[qq] = p2h[mr][j] * p1p3h[mr][qq];
          a[mr] = pk.h8;
        }
        __builtin_amdgcn_s_setprio(1);
#pragma unroll
        for (int mr = 0; mr < 2; ++mr)
#pragma unroll
          for (int nf = 0; nf < 3; ++nf)
            acc[mr][nf] = __builtin_amdgcn_mfma_f32_32x32x16_f16(a[mr], b[s][nf], acc[mr][nf], 0, 0, 0);
        __builtin_amdgcn_s_setprio(0);
      }
      asm volatile("s_waitcnt vmcnt(0)" ::: "memory");
      __builtin_amdgcn_s_barrier();
    }
  }

  // epilogue: 32x32 C/D: col = lane&31, row = (reg&3)+8*(reg>>2)+4*(lane>>5)
#pragma unroll
  for (int mr = 0; mr < 2; ++mr)
#pragma unroll
    for (int nf = 0; nf < 3; ++nf)
#pragma unroll
      for (int reg = 0; reg < 16; ++reg) {
        const int row = (reg & 3) + 8 * (reg >> 2) + 4 * g;
        const int t = m0 + wm * 64 + mr * 32 + row;
        out[(size_t)t * 768 + n0 + wn * 96 + nf * 32 + l31] = acc[mr][nf][reg];
      }
}

// ---------------------------------------------------------------------------
extern "C" void kernel_launch(void* const* d_in, const int* in_sizes, int n_in,
                              void* d_out, int out_size, void* d_ws, size_t ws_size,
                              hipStream_t stream) {
  (void)in_sizes; (void)n_in; (void)out_size; (void)ws_size;
  const float* x    = (const float*)d_in[0];
  const float* W1   = (const float*)d_in[1];
  const float* b1   = (const float*)d_in[2];
  const float* W2   = (const float*)d_in[3];
  const float* b2   = (const float*)d_in[4];
  const float* W3   = (const float*)d_in[5];
  const float* b3   = (const float*)d_in[6];
  const float* grid = (const float*)d_in[7];
  const float* temp = (const float*)d_in[8];
  float* out = (float*)d_out;

  // ws: gT f16 [768][4096] = 6,291,456 B ; p f32 [16384][52] = 3,407,872 B ;
  //     wfrag f16 = 73,728 B
  ushort_t* gT = (ushort_t*)d_ws;
  float* p = (float*)((char*)d_ws + 6291456);
  ushort_t* wfrag = (ushort_t*)((char*)d_ws + 6291456 + 3407872);

  k_pack<<<dim3(64, 13), 256, 0, stream>>>(grid, gT, W1, W2, W3, wfrag);
  k_prep<<<dim3(256), 256, 0, stream>>>(x, wfrag, b1, b2, b3, temp, p);
  k_gemm<<<dim3(128, 4), 256, 0, stream>>>(p, gT, out);
}

// Round 18
// 107.061 us; speedup vs baseline: 1.2025x; 1.1110x over previous
//
#include <hip/hip_runtime.h>
#include <hip/hip_bf16.h>

// out[t,l] = sum_{ijk} p1[t,i] p2[t,j] p3[t,k] grid[i,j,k,l]
// GEMM M=16384, K=4096 (k=i*256+j*16+kk), N=768; A built in registers.
// v17 = v13 verbatim (champion: 95us gemm, 106us total; measured twice).
// Schedule note (v16 lesson): stage-issue must come AFTER the ds_reads --
// its LDS writes then land during the MFMA phase (LDS pipe idle), not
// during the ds_read phase (LDS pipe critical).

using f32x2  = __attribute__((ext_vector_type(2))) float;
using f32x4  = __attribute__((ext_vector_type(4))) float;
using f32x16 = __attribute__((ext_vector_type(16))) float;
using half8  = __attribute__((ext_vector_type(8))) _Float16;
using half2v = __attribute__((ext_vector_type(2))) _Float16;
typedef unsigned short ushort_t;
typedef unsigned int uint_t;

typedef const __attribute__((address_space(1))) void* gptr_t;
typedef __attribute__((address_space(3))) void* lptr_t;

#define PSTRIDE 52            // p row stride (floats)

static __device__ __forceinline__ ushort_t f2h_bits(float x) {
  union { _Float16 h; ushort_t u; } c;
  c.h = (_Float16)x;          // RNE
  return c.u;
}

static __device__ __forceinline__ half2v cvt_pkrtz2(float a, float b) {
  auto r = __builtin_amdgcn_cvt_pkrtz(a, b);
  union { decltype(r) i; half2v o; } u;
  u.i = r;
  return u.o;
}

// ---------------------------------------------------------------------------
// Kernel 1: grid transpose -> gT f16 [by=0..11]; W -> wfrag B-frags [by=12]
// ---------------------------------------------------------------------------
__global__ __launch_bounds__(256) void k_pack(const float* __restrict__ g,
                                              ushort_t* __restrict__ gT,
                                              const float* __restrict__ W1,
                                              const float* __restrict__ W2,
                                              const float* __restrict__ W3,
                                              ushort_t* __restrict__ wfrag) {
  const int tx = threadIdx.x;
  if (blockIdx.y == 12) {
    if (blockIdx.x >= 9) return;
#pragma unroll
    for (int j = 0; j < 16; ++j) {
      const int u = blockIdx.x * 4096 + tx * 16 + j;   // 0..36863
      const int e = u & 7;
      const int l = (u >> 3) & 63;
      const int frag = u >> 9;                         // ks*3+nf
      const int ks = frag / 3, nf = frag % 3;
      const int d = ks * 32 + 8 * (l >> 4) + e;
      const int col = l & 15;
      const float* Wsel = (nf == 0) ? W1 : (nf == 1) ? W2 : W3;
      wfrag[u] = f2h_bits(Wsel[d * 16 + col]);
    }
    return;
  }
  __shared__ ushort_t tile[64][65];
  const int r0 = blockIdx.x * 64;   // ijk base
  const int c0 = blockIdx.y * 64;   // l base
#pragma unroll
  for (int it = 0; it < 4; ++it) {
    const int idx = tx + it * 256;
    const int r = idx >> 4;
    const int c = (idx & 15) << 2;
    const float4 v = *(const float4*)(g + (size_t)(r0 + r) * 768 + (c0 + c));
    tile[c + 0][r] = f2h_bits(v.x);
    tile[c + 1][r] = f2h_bits(v.y);
    tile[c + 2][r] = f2h_bits(v.z);
    tile[c + 3][r] = f2h_bits(v.w);
  }
  __syncthreads();
#pragma unroll
  for (int it = 0; it < 4; ++it) {
    const int idx = tx + it * 256;
    const int r = idx >> 4;
    const int c = (idx & 15) << 2;
    ushort4 o;
    o.x = tile[r][c + 0]; o.y = tile[r][c + 1];
    o.z = tile[r][c + 2]; o.w = tile[r][c + 3];
    *(ushort4*)(gT + (size_t)(c0 + r) * 4096 + (r0 + c)) = o;
  }
}

// ---------------------------------------------------------------------------
// Kernel 2: MFMA prep. p[t][48] = softmax16((x@W+b)/temp) per 16-group.
// ---------------------------------------------------------------------------
__global__ __launch_bounds__(256) void k_prep(const float* __restrict__ x,
                                              const ushort_t* __restrict__ wfrag,
                                              const float* __restrict__ b1,
                                              const float* __restrict__ b2,
                                              const float* __restrict__ b3,
                                              const float* __restrict__ temp,
                                              float* __restrict__ p) {
  const int tid = threadIdx.x;
  const int lane = tid & 63;
  const int wv = tid >> 6;
  const int t0w = blockIdx.x * 64 + wv * 16;  // wave's token base
  const int m = lane & 15;                    // A row / C col
  const int q = lane >> 4;                    // 0..3

  const float* xrow = x + (size_t)(t0w + m) * 768 + q * 8;

  f32x4 acc[3];
#pragma unroll
  for (int nf = 0; nf < 3; ++nf) acc[nf] = (f32x4){0.f, 0.f, 0.f, 0.f};

  const ushort_t* wf = wfrag + lane * 8;
#pragma unroll
  for (int ks = 0; ks < 24; ++ks) {
    const f32x4 xa = *(const f32x4*)(xrow + ks * 32);
    const f32x4 xb = *(const f32x4*)(xrow + ks * 32 + 4);
    union { half2v h2[4]; half8 h8; } pk;
    pk.h2[0] = cvt_pkrtz2(xa[0], xa[1]);
    pk.h2[1] = cvt_pkrtz2(xa[2], xa[3]);
    pk.h2[2] = cvt_pkrtz2(xb[0], xb[1]);
    pk.h2[3] = cvt_pkrtz2(xb[2], xb[3]);
    const half8 a = pk.h8;
#pragma unroll
    for (int nf = 0; nf < 3; ++nf) {
      const half8 w = *(const half8*)&wf[(size_t)(ks * 3 + nf) * 512];
      acc[nf] = __builtin_amdgcn_mfma_f32_16x16x32_f16(a, w, acc[nf], 0, 0, 0);
    }
  }

  const float invT = 1.0f / temp[0];
  float z[3][4];
  const float bias[3] = {b1[m], b2[m], b3[m]};
#pragma unroll
  for (int nf = 0; nf < 3; ++nf)
#pragma unroll
    for (int r = 0; r < 4; ++r) z[nf][r] = (acc[nf][r] + bias[nf]) * invT;

#pragma unroll
  for (int grp = 0; grp < 3; ++grp) {
    float mx[4], sm[4];
#pragma unroll
    for (int r = 0; r < 4; ++r) mx[r] = z[grp][r];
#pragma unroll
    for (int msk = 1; msk < 16; msk <<= 1)
#pragma unroll
      for (int r = 0; r < 4; ++r) mx[r] = fmaxf(mx[r], __shfl_xor(mx[r], msk));
#pragma unroll
    for (int r = 0; r < 4; ++r) { z[grp][r] = __expf(z[grp][r] - mx[r]); sm[r] = z[grp][r]; }
#pragma unroll
    for (int msk = 1; msk < 16; msk <<= 1)
#pragma unroll
      for (int r = 0; r < 4; ++r) sm[r] += __shfl_xor(sm[r], msk);
#pragma unroll
    for (int r = 0; r < 4; ++r) z[grp][r] /= sm[r];
  }

#pragma unroll
  for (int r = 0; r < 4; ++r) {
    float* prow = p + (size_t)(t0w + 4 * q + r) * PSTRIDE + m;
#pragma unroll
    for (int grp = 0; grp < 3; ++grp) prow[grp * 16] = z[grp][r];
  }
}

// ---------------------------------------------------------------------------
// Kernel 3: GEMM champion. BM=128 BN=192 BK=64, 4 waves 2x2, wave tile
// 64x96, mfma_32x32x16_f16, 2-buffer drain loop: 12 ds_reads -> stage(kt+1)
// -> 4 setprio clusters of 6 MFMA -> vmcnt(0) -> barrier. XCD swizzle.
// ---------------------------------------------------------------------------
__global__ __launch_bounds__(256, 2) void k_gemm(const float* __restrict__ p_g,
                                                 const ushort_t* __restrict__ gT,
                                                 float* __restrict__ out) {
  __shared__ ushort_t Bt[2][192 * 64];        // 49,152 B
  __shared__ float p1T[16 * 128];             //  8,192 B

  const int tid = threadIdx.x;
  const int lane = tid & 63;
  const int wv = __builtin_amdgcn_readfirstlane(tid >> 6);
  const int wm = wv >> 1, wn = wv & 1;
  const int g = lane >> 5;                    // k-half 0/1
  const int l31 = lane & 31;

  // XCD-aware swizzle over 512 blocks (512 % 8 == 0 -> bijective)
  const int f = blockIdx.y * 128 + blockIdx.x;
  const int w = (f & 7) * 64 + (f >> 3);
  const int m0 = (w & 127) * 128;
  const int n0 = (w >> 7) * 192;

  // p1T[i][row] cooperative build (f32)
  if (tid < 128) {
    const float* pr = p_g + (size_t)(m0 + tid) * PSTRIDE;
#pragma unroll
    for (int qq = 0; qq < 4; ++qq) {
      const f32x4 v = *(const f32x4*)(pr + qq * 4);
#pragma unroll
      for (int e = 0; e < 4; ++e) p1T[(qq * 4 + e) * 128 + tid] = v[e];
    }
  }

  // per-lane p2 (16 f16-broadcast pairs) and p3 (own k-half, 8 f32) per m-rep
  const int rowA0 = m0 + wm * 64 + l31;
  half2v p2h[2][16];
  float p3r[2][8];
#pragma unroll
  for (int mr = 0; mr < 2; ++mr) {
    const float* pr = p_g + (size_t)(rowA0 + mr * 32) * PSTRIDE;
#pragma unroll
    for (int qq = 0; qq < 4; ++qq) {
      const f32x4 v = *(const f32x4*)(pr + 16 + qq * 4);
#pragma unroll
      for (int e = 0; e < 4; ++e)
        p2h[mr][qq * 4 + e] = cvt_pkrtz2(v[e], v[e]);
    }
#pragma unroll
    for (int qq = 0; qq < 2; ++qq) {
      const f32x4 v = *(const f32x4*)(pr + 32 + 8 * g + qq * 4);
      p3r[mr][qq * 4 + 0] = v[0]; p3r[mr][qq * 4 + 1] = v[1];
      p3r[mr][qq * 4 + 2] = v[2]; p3r[mr][qq * 4 + 3] = v[3];
    }
  }

  // B staging: linear LDS dest + inverse-swizzled source (16B chunks)
  const int srow = wv * 48 + (lane >> 3);
  const int schunk = (lane & 7) ^ (lane >> 3);
  const ushort_t* sbase = gT + (size_t)(n0 + srow) * 4096 + schunk * 8;
  auto stage = [&](int buf, int kt) {
    const ushort_t* src = sbase + kt * 64;
#pragma unroll
    for (int qq = 0; qq < 6; ++qq) {
      __builtin_amdgcn_global_load_lds((gptr_t)(src + (size_t)qq * 8 * 4096),
                                       (lptr_t)&Bt[buf][(wv * 48 + qq * 8) * 64], 16, 0, 0);
    }
  };

  f32x16 acc[2][3];
#pragma unroll
  for (int mr = 0; mr < 2; ++mr)
#pragma unroll
    for (int nf = 0; nf < 3; ++nf)
#pragma unroll
      for (int e = 0; e < 16; ++e) acc[mr][nf][e] = 0.f;

  stage(0, 0);
  asm volatile("s_waitcnt vmcnt(0) lgkmcnt(0)" ::: "memory");
  __builtin_amdgcn_s_barrier();

  const int rowLoc0 = wm * 64 + l31;
  for (int io = 0; io < 16; ++io) {           // i-index (p1)
    half2v p1p3h[2][4];
#pragma unroll
    for (int mr = 0; mr < 2; ++mr) {
      const float p1v = p1T[io * 128 + rowLoc0 + mr * 32];
#pragma unroll
      for (int qq = 0; qq < 4; ++qq)
        p1p3h[mr][qq] = cvt_pkrtz2(p1v * p3r[mr][2 * qq],
                                   p1v * p3r[mr][2 * qq + 1]);
    }
#pragma unroll
    for (int kq = 0; kq < 4; ++kq) {
      const int kt = io * 4 + kq;
      const ushort_t* bbuf = Bt[kq & 1];

      // all 12 B-fragment reads up front (counted lgkm waits by compiler)
      half8 b[4][3];
#pragma unroll
      for (int s = 0; s < 4; ++s) {
        const int cd = 2 * s + g;
#pragma unroll
        for (int nf = 0; nf < 3; ++nf) {
          const int r = wn * 96 + nf * 32 + l31;
          b[s][nf] = *(const half8*)&bbuf[r * 64 + ((cd ^ (r & 7)) << 3)];
        }
      }
      // prefetch next K64 tile (after ds_reads: DMA LDS-writes land during
      // the MFMA phase, off the LDS critical path — v16 lesson)
      if (kq < 3 || io < 15) stage((kq + 1) & 1, kt + 1);

#pragma unroll
      for (int s = 0; s < 4; ++s) {
        const int j = kq * 4 + s;             // static p2 index
        half8 a[2];
#pragma unroll
        for (int mr = 0; mr < 2; ++mr) {
          union { half2v h2[4]; half8 h8; } pk;
#pragma unroll
          for (int qq = 0; qq < 4; ++qq) pk.h2[qq] = p2h[mr][j] * p1p3h[mr][qq];
          a[mr] = pk.h8;
        }
        __builtin_amdgcn_s_setprio(1);
#pragma unroll
        for (int mr = 0; mr < 2; ++mr)
#pragma unroll
          for (int nf = 0; nf < 3; ++nf)
            acc[mr][nf] = __builtin_amdgcn_mfma_f32_32x32x16_f16(a[mr], b[s][nf], acc[mr][nf], 0, 0, 0);
        __builtin_amdgcn_s_setprio(0);
      }
      asm volatile("s_waitcnt vmcnt(0)" ::: "memory");
      __builtin_amdgcn_s_barrier();
    }
  }

  // epilogue: 32x32 C/D: col = lane&31, row = (reg&3)+8*(reg>>2)+4*(lane>>5)
#pragma unroll
  for (int mr = 0; mr < 2; ++mr)
#pragma unroll
    for (int nf = 0; nf < 3; ++nf)
#pragma unroll
      for (int reg = 0; reg < 16; ++reg) {
        const int row = (reg & 3) + 8 * (reg >> 2) + 4 * g;
        const int t = m0 + wm * 64 + mr * 32 + row;
        out[(size_t)t * 768 + n0 + wn * 96 + nf * 32 + l31] = acc[mr][nf][reg];
      }
}

// ---------------------------------------------------------------------------
extern "C" void kernel_launch(void* const* d_in, const int* in_sizes, int n_in,
                              void* d_out, int out_size, void* d_ws, size_t ws_size,
                              hipStream_t stream) {
  (void)in_sizes; (void)n_in; (void)out_size; (void)ws_size;
  const float* x    = (const float*)d_in[0];
  const float* W1   = (const float*)d_in[1];
  const float* b1   = (const float*)d_in[2];
  const float* W2   = (const float*)d_in[3];
  const float* b2   = (const float*)d_in[4];
  const float* W3   = (const float*)d_in[5];
  const float* b3   = (const float*)d_in[6];
  const float* grid = (const float*)d_in[7];
  const float* temp = (const float*)d_in[8];
  float* out = (float*)d_out;

  // ws: gT f16 [768][4096] = 6,291,456 B ; p f32 [16384][52] = 3,407,872 B ;
  //     wfrag f16 = 73,728 B
  ushort_t* gT = (ushort_t*)d_ws;
  float* p = (float*)((char*)d_ws + 6291456);
  ushort_t* wfrag = (ushort_t*)((char*)d_ws + 6291456 + 3407872);

  k_pack<<<dim3(64, 13), 256, 0, stream>>>(grid, gT, W1, W2, W3, wfrag);
  k_prep<<<dim3(256), 256, 0, stream>>>(x, wfrag, b1, b2, b3, temp, p);
  k_gemm<<<dim3(128, 4), 256, 0, stream>>>(p, gT, out);
}